// Round 1
// baseline (724.866 us; speedup 1.0000x reference)
//
#include <hip/hip_runtime.h>
#include <math.h>

#define BB 32
#define SS 4096
#define HH 1024
#define CHUNKS 32                      // blocks per batch
#define ROWS_PER_BLOCK (SS / CHUNKS)   // 128
#define WAVES 4
#define ROWS_PER_WAVE (ROWS_PER_BLOCK / WAVES)  // 32
#define U 8                            // rows per batch (butterfly chains interleaved)

// pw = exp(tanh(s)); tanh via exp+rcp (no branches, no precise div).
// tanh bounds energy to [-1,1] so no softmax max-subtraction is needed.
__device__ __forceinline__ float softmax_w(float s) {
    float t  = __expf(2.0f * s);                              // v_exp_f32
    float th = 1.0f - 2.0f * __builtin_amdgcn_rcpf(t + 1.0f); // v_rcp_f32
    return __expf(th);
}

// Pass 1: fused energy + un-normalized softmax-weighted accumulation.
// Structure: per 8-row batch, (1) stream rows for the dot product only
// (32 independent loads in flight, no row residency in registers),
// (2) 8 butterfly reduce chains interleaved (6 steps amortized),
// (3) re-read the same 32 KB (L2-hot, ~1-2k cycle reuse distance) for the
// weighted accumulate. Low fixed register state -> 4 waves/SIMD resident.
__global__ __launch_bounds__(256, 4) void attn_pass1(
    const float* __restrict__ x, const float* __restrict__ w,
    float* __restrict__ pc, float* __restrict__ pl)
{
    const int tid  = threadIdx.x;
    const int wave = tid >> 6;
    const int lane = tid & 63;
    const int blk  = blockIdx.x;            // b*CHUNKS + chunk
    const int b    = blk / CHUNKS;
    const int chunk= blk % CHUNKS;

    const float* xb = x + (long long)b * SS * HH
                        + (long long)chunk * ROWS_PER_BLOCK * HH
                        + (long long)wave * ROWS_PER_WAVE * HH
                        + lane * 4;

    float4 wv[4];
#pragma unroll
    for (int k = 0; k < 4; ++k)
        wv[k] = *(const float4*)(w + k * 256 + lane * 4);

    float4 acc[4];
#pragma unroll
    for (int k = 0; k < 4; ++k) acc[k] = make_float4(0.f, 0.f, 0.f, 0.f);
    float l = 0.f;

    for (int r = 0; r < ROWS_PER_WAVE; r += U) {
        const float* xr = xb + (long long)r * HH;

        // ---- dot phase: stream 8 rows, values not kept ----
        float t[U];
#pragma unroll
        for (int u = 0; u < U; ++u) t[u] = 0.f;

#pragma unroll
        for (int k = 0; k < 4; ++k) {
            float4 v[U];
#pragma unroll
            for (int u = 0; u < U; ++u)
                v[u] = *(const float4*)(xr + (long long)u * HH + k * 256);
#pragma unroll
            for (int u = 0; u < U; ++u) {
                t[u] = fmaf(v[u].x, wv[k].x, t[u]);
                t[u] = fmaf(v[u].y, wv[k].y, t[u]);
                t[u] = fmaf(v[u].z, wv[k].z, t[u]);
                t[u] = fmaf(v[u].w, wv[k].w, t[u]);
            }
        }

        // ---- 64-lane butterfly reduce, 8 independent chains interleaved ----
#pragma unroll
        for (int off = 32; off >= 1; off >>= 1)
#pragma unroll
            for (int u = 0; u < U; ++u)
                t[u] += __shfl_xor(t[u], off, 64);

        float p[U];
#pragma unroll
        for (int u = 0; u < U; ++u) {
            p[u] = softmax_w(t[u]);
            l += p[u];
        }

        // ---- accumulate phase: re-read same 32 KB (L2-hot) ----
#pragma unroll
        for (int k = 0; k < 4; ++k) {
            float4 v[U];
#pragma unroll
            for (int u = 0; u < U; ++u)
                v[u] = *(const float4*)(xr + (long long)u * HH + k * 256);
#pragma unroll
            for (int u = 0; u < U; ++u) {
                acc[k].x = fmaf(p[u], v[u].x, acc[k].x);
                acc[k].y = fmaf(p[u], v[u].y, acc[k].y);
                acc[k].z = fmaf(p[u], v[u].z, acc[k].z);
                acc[k].w = fmaf(p[u], v[u].w, acc[k].w);
            }
        }
    }

    // Block-level reduce across the 4 waves via LDS, one partial per block.
    __shared__ float lds_c[WAVES * HH];   // 16 KB
    __shared__ float lds_l[WAVES];
#pragma unroll
    for (int k = 0; k < 4; ++k)
        *(float4*)(lds_c + wave * HH + k * 256 + lane * 4) = acc[k];
    if (lane == 0) lds_l[wave] = l;       // l is lane-replicated in a wave
    __syncthreads();

    float4 c = *(const float4*)(lds_c + tid * 4);
#pragma unroll
    for (int wv2 = 1; wv2 < WAVES; ++wv2) {
        float4 o = *(const float4*)(lds_c + wv2 * HH + tid * 4);
        c.x += o.x; c.y += o.y; c.z += o.z; c.w += o.w;
    }
    *(float4*)(pc + (long long)blk * HH + tid * 4) = c;
    if (tid == 0)
        pl[blk] = lds_l[0] + lds_l[1] + lds_l[2] + lds_l[3];
}

// Pass 2: combine CHUNKS partials per batch, normalize.
__global__ __launch_bounds__(256) void attn_pass2(
    const float* __restrict__ pc, const float* __restrict__ pl,
    float* __restrict__ out)
{
    const int b = blockIdx.x;
    const int t = threadIdx.x;
    float l = 0.f;
    float4 c = make_float4(0.f, 0.f, 0.f, 0.f);
#pragma unroll
    for (int i = 0; i < CHUNKS; ++i) {
        const int blk = b * CHUNKS + i;
        l += pl[blk];
        float4 o = *(const float4*)(pc + (long long)blk * HH + t * 4);
        c.x += o.x; c.y += o.y; c.z += o.z; c.w += o.w;
    }
    const float inv = 1.f / l;
    float4 r = make_float4(c.x * inv, c.y * inv, c.z * inv, c.w * inv);
    *(float4*)(out + (long long)b * HH + t * 4) = r;
}

extern "C" void kernel_launch(void* const* d_in, const int* in_sizes, int n_in,
                              void* d_out, int out_size, void* d_ws, size_t ws_size,
                              hipStream_t stream) {
    const float* x = (const float*)d_in[0];   // [B,S,H] fp32
    const float* w = (const float*)d_in[1];   // [H] fp32
    float* out = (float*)d_out;               // [B,H] fp32

    float* pc = (float*)d_ws;                           // [B*CHUNKS, H]
    float* pl = pc + (size_t)BB * CHUNKS * HH;          // [B*CHUNKS]

    attn_pass1<<<BB * CHUNKS, 256, 0, stream>>>(x, w, pc, pl);
    attn_pass2<<<BB, 256, 0, stream>>>(pc, pl, out);
}

// Round 2
// 682.461 us; speedup vs baseline: 1.0621x; 1.0621x over previous
//
#include <hip/hip_runtime.h>
#include <math.h>

#define BB 32
#define SS 4096
#define HH 1024
#define CHUNKS 32                      // blocks per batch
#define ROWS_PER_BLOCK (SS / CHUNKS)   // 128
#define WAVES 4
#define ROWS_PER_WAVE (ROWS_PER_BLOCK / WAVES)  // 32
#define U 8                            // rows per batch, register-resident

// pw = exp(tanh(s)); tanh via exp+rcp (no branches, no precise div).
// tanh bounds energy to [-1,1] so no softmax max-subtraction is needed.
__device__ __forceinline__ float softmax_w(float s) {
    float t  = __expf(2.0f * s);                              // v_exp_f32
    float th = 1.0f - 2.0f * __builtin_amdgcn_rcpf(t + 1.0f); // v_rcp_f32
    return __expf(th);
}

// Pass 1: fused energy + un-normalized softmax-weighted accumulation.
// Single read of x: each 8-row batch is loaded once into registers
// (32 independent dwordx4 in flight), used for the dot, then for the
// weighted accumulate. 8 butterfly chains interleaved amortize the
// 6-step shuffle reduce across 8 rows.
// Registers: 128 (row buffer) + ~60 fixed -> ~190, fits 2 waves/SIMD cap.
// Grid 1024 blocks at 2 blocks/CU = exactly 2 residency rounds, no tail.
__global__ __launch_bounds__(256, 2) void attn_pass1(
    const float* __restrict__ x, const float* __restrict__ w,
    float* __restrict__ pc, float* __restrict__ pl)
{
    const int tid  = threadIdx.x;
    const int wave = tid >> 6;
    const int lane = tid & 63;
    const int blk  = blockIdx.x;            // b*CHUNKS + chunk
    const int b    = blk / CHUNKS;
    const int chunk= blk % CHUNKS;

    const float* xb = x + (long long)b * SS * HH
                        + (long long)chunk * ROWS_PER_BLOCK * HH
                        + (long long)wave * ROWS_PER_WAVE * HH
                        + lane * 4;

    float4 wv[4];
#pragma unroll
    for (int k = 0; k < 4; ++k)
        wv[k] = *(const float4*)(w + k * 256 + lane * 4);

    float4 acc[4];
#pragma unroll
    for (int k = 0; k < 4; ++k) acc[k] = make_float4(0.f, 0.f, 0.f, 0.f);
    float l = 0.f;

#pragma unroll 1
    for (int r = 0; r < ROWS_PER_WAVE; r += U) {
        const float* xr = xb + (long long)r * HH;

        // ---- load phase: 32 independent dwordx4, all in flight ----
        float4 v[U][4];
#pragma unroll
        for (int u = 0; u < U; ++u)
#pragma unroll
            for (int k = 0; k < 4; ++k)
                v[u][k] = *(const float4*)(xr + (long long)u * HH + k * 256);

        // ---- dot phase ----
        float t[U];
#pragma unroll
        for (int u = 0; u < U; ++u) t[u] = 0.f;
#pragma unroll
        for (int k = 0; k < 4; ++k)
#pragma unroll
            for (int u = 0; u < U; ++u) {
                t[u] = fmaf(v[u][k].x, wv[k].x, t[u]);
                t[u] = fmaf(v[u][k].y, wv[k].y, t[u]);
                t[u] = fmaf(v[u][k].z, wv[k].z, t[u]);
                t[u] = fmaf(v[u][k].w, wv[k].w, t[u]);
            }

        // ---- 64-lane butterfly reduce, 8 independent chains interleaved ----
#pragma unroll
        for (int off = 32; off >= 1; off >>= 1)
#pragma unroll
            for (int u = 0; u < U; ++u)
                t[u] += __shfl_xor(t[u], off, 64);

        float p[U];
#pragma unroll
        for (int u = 0; u < U; ++u) {
            p[u] = softmax_w(t[u]);
            l += p[u];
        }

        // ---- accumulate phase: rows still in registers ----
#pragma unroll
        for (int k = 0; k < 4; ++k)
#pragma unroll
            for (int u = 0; u < U; ++u) {
                acc[k].x = fmaf(p[u], v[u][k].x, acc[k].x);
                acc[k].y = fmaf(p[u], v[u][k].y, acc[k].y);
                acc[k].z = fmaf(p[u], v[u][k].z, acc[k].z);
                acc[k].w = fmaf(p[u], v[u][k].w, acc[k].w);
            }
    }

    // Block-level reduce across the 4 waves via LDS, one partial per block.
    __shared__ float lds_c[WAVES * HH];   // 16 KB
    __shared__ float lds_l[WAVES];
#pragma unroll
    for (int k = 0; k < 4; ++k)
        *(float4*)(lds_c + wave * HH + k * 256 + lane * 4) = acc[k];
    if (lane == 0) lds_l[wave] = l;       // l is lane-replicated in a wave
    __syncthreads();

    float4 c = *(const float4*)(lds_c + tid * 4);
#pragma unroll
    for (int wv2 = 1; wv2 < WAVES; ++wv2) {
        float4 o = *(const float4*)(lds_c + wv2 * HH + tid * 4);
        c.x += o.x; c.y += o.y; c.z += o.z; c.w += o.w;
    }
    *(float4*)(pc + (long long)blk * HH + tid * 4) = c;
    if (tid == 0)
        pl[blk] = lds_l[0] + lds_l[1] + lds_l[2] + lds_l[3];
}

// Pass 2: combine CHUNKS partials per batch, normalize.
__global__ __launch_bounds__(256) void attn_pass2(
    const float* __restrict__ pc, const float* __restrict__ pl,
    float* __restrict__ out)
{
    const int b = blockIdx.x;
    const int t = threadIdx.x;
    float l = 0.f;
    float4 c = make_float4(0.f, 0.f, 0.f, 0.f);
#pragma unroll
    for (int i = 0; i < CHUNKS; ++i) {
        const int blk = b * CHUNKS + i;
        l += pl[blk];
        float4 o = *(const float4*)(pc + (long long)blk * HH + t * 4);
        c.x += o.x; c.y += o.y; c.z += o.z; c.w += o.w;
    }
    const float inv = 1.f / l;
    float4 r = make_float4(c.x * inv, c.y * inv, c.z * inv, c.w * inv);
    *(float4*)(out + (long long)b * HH + t * 4) = r;
}

extern "C" void kernel_launch(void* const* d_in, const int* in_sizes, int n_in,
                              void* d_out, int out_size, void* d_ws, size_t ws_size,
                              hipStream_t stream) {
    const float* x = (const float*)d_in[0];   // [B,S,H] fp32
    const float* w = (const float*)d_in[1];   // [H] fp32
    float* out = (float*)d_out;               // [B,H] fp32

    float* pc = (float*)d_ws;                           // [B*CHUNKS, H]
    float* pl = pc + (size_t)BB * CHUNKS * HH;          // [B*CHUNKS]

    attn_pass1<<<BB * CHUNKS, 256, 0, stream>>>(x, w, pc, pl);
    attn_pass2<<<BB, 256, 0, stream>>>(pc, pl, out);
}

// Round 4
// 676.167 us; speedup vs baseline: 1.0720x; 1.0093x over previous
//
#include <hip/hip_runtime.h>
#include <math.h>
#include <stdint.h>

#define BB 32
#define SS 4096
#define HH 1024
#define CHUNKS 32                      // blocks per batch
#define ROWS_PER_BLOCK (SS / CHUNKS)   // 128
#define WAVES 4
#define ROWS_PER_WAVE (ROWS_PER_BLOCK / WAVES)  // 32
#define NBUF 4                         // LDS ring stages per wave (1 row = 4 KB each)

typedef __attribute__((ext_vector_type(4))) float f32x4;

// pw = exp(tanh(s)); tanh via exp+rcp. tanh bounds energy to [-1,1] so no
// softmax max-subtraction is needed.
__device__ __forceinline__ float softmax_w(float s) {
    float t  = __expf(2.0f * s);                              // v_exp_f32
    float th = 1.0f - 2.0f * __builtin_amdgcn_rcpf(t + 1.0f); // v_rcp_f32
    return __expf(th);
}

// 32-bit LDS byte offset of a generic pointer known to point into LDS.
__device__ __forceinline__ unsigned lds_base_off(const void* p) {
    return (unsigned)(uintptr_t)(__attribute__((address_space(3))) const char*)p;
}

// Inline-asm LDS read: invisible to the compiler's LDS-DMA alias analysis,
// so it cannot insert a conservative s_waitcnt vmcnt(0) drain before it.
__device__ __forceinline__ f32x4 lds_read_b128(unsigned byte_off) {
    f32x4 r;
    asm volatile("ds_read_b128 %0, %1" : "=&v"(r) : "v"(byte_off));
    return r;
}

// One row (4 KB) -> LDS via 4x global_load_lds width-16 (no dest VGPRs:
// the compiler cannot sink/serialize these). LDS dest is wave-uniform
// base + lane*16; global src is per-lane.
__device__ __forceinline__ void issue_row(const float* gl, float* lbase) {
#pragma unroll
    for (int j = 0; j < 4; ++j)
        __builtin_amdgcn_global_load_lds(
            (const __attribute__((address_space(1))) void*)(gl + j * 256),
            (__attribute__((address_space(3))) void*)(lbase + j * 256),
            16, 0, 0);
}

// Pass 1: fused energy + un-normalized softmax-weighted accumulation.
// Per-wave 4-stage LDS DMA ring: stage r+3 is issued before consuming
// stage r, and the steady-state wait is counted vmcnt(12) (3 stages =
// 12 KB/wave always in flight; 8 waves/CU -> 96 KB/CU outstanding).
__global__ __launch_bounds__(256, 2) void attn_pass1(
    const float* __restrict__ x, const float* __restrict__ w,
    float* __restrict__ pc, float* __restrict__ pl)
{
    const int tid  = threadIdx.x;
    const int wave = tid >> 6;
    const int lane = tid & 63;
    const int blk  = blockIdx.x;            // b*CHUNKS + chunk
    const int b    = blk / CHUNKS;
    const int chunk= blk % CHUNKS;

    __shared__ float smem[WAVES * NBUF * 1024];   // 64 KB ring (reused for epilogue)
    __shared__ float lds_l[WAVES];

    // this wave's 32 contiguous rows
    const float* xw = x + (long long)b * SS * HH
                        + (long long)chunk * ROWS_PER_BLOCK * HH
                        + (long long)wave * ROWS_PER_WAVE * HH;
    const float* gl = xw + lane * 4;              // per-lane global address
    float* ring = smem + wave * (NBUF * 1024);

    // w fragment; drain its loads so vmcnt counting below is exact.
    float4 wv[4];
#pragma unroll
    for (int k = 0; k < 4; ++k)
        wv[k] = *(const float4*)(w + k * 256 + lane * 4);
    asm volatile("s_waitcnt vmcnt(0)");
    __builtin_amdgcn_sched_barrier(0);

    // prologue: stages 0..2 in flight
#pragma unroll
    for (int s = 0; s < NBUF - 1; ++s)
        issue_row(gl + (long long)s * HH, ring + s * 1024);
    __builtin_amdgcn_sched_barrier(0);

    float4 acc[4];
#pragma unroll
    for (int k = 0; k < 4; ++k) acc[k] = make_float4(0.f, 0.f, 0.f, 0.f);
    float l = 0.f;

    const unsigned ring_off = lds_base_off(ring) + lane * 16;

#pragma unroll 1
    for (int r = 0; r < ROWS_PER_WAVE; ++r) {
        const int buf = r & (NBUF - 1);

        if (r + 3 < ROWS_PER_WAVE) {
            issue_row(gl + (long long)(r + 3) * HH, ring + ((r + 3) & (NBUF - 1)) * 1024);
            __builtin_amdgcn_sched_barrier(0);
            asm volatile("s_waitcnt vmcnt(12)");   // stages r+1..r+3 stay in flight
        } else if (r == ROWS_PER_WAVE - 3) {
            asm volatile("s_waitcnt vmcnt(8)");
        } else if (r == ROWS_PER_WAVE - 2) {
            asm volatile("s_waitcnt vmcnt(4)");
        } else {
            asm volatile("s_waitcnt vmcnt(0)");
        }
        __builtin_amdgcn_sched_barrier(0);

        const unsigned base = ring_off + buf * 4096;
        f32x4 v0 = lds_read_b128(base);
        f32x4 v1 = lds_read_b128(base + 1024);
        f32x4 v2 = lds_read_b128(base + 2048);
        f32x4 v3 = lds_read_b128(base + 3072);
        asm volatile("s_waitcnt lgkmcnt(0)");
        __builtin_amdgcn_sched_barrier(0);

        // dot with w
        float t = 0.f;
        t = fmaf(v0.x, wv[0].x, t); t = fmaf(v0.y, wv[0].y, t);
        t = fmaf(v0.z, wv[0].z, t); t = fmaf(v0.w, wv[0].w, t);
        t = fmaf(v1.x, wv[1].x, t); t = fmaf(v1.y, wv[1].y, t);
        t = fmaf(v1.z, wv[1].z, t); t = fmaf(v1.w, wv[1].w, t);
        t = fmaf(v2.x, wv[2].x, t); t = fmaf(v2.y, wv[2].y, t);
        t = fmaf(v2.z, wv[2].z, t); t = fmaf(v2.w, wv[2].w, t);
        t = fmaf(v3.x, wv[3].x, t); t = fmaf(v3.y, wv[3].y, t);
        t = fmaf(v3.z, wv[3].z, t); t = fmaf(v3.w, wv[3].w, t);

        // 64-lane butterfly reduce
#pragma unroll
        for (int off = 32; off >= 1; off >>= 1)
            t += __shfl_xor(t, off, 64);

        const float p = softmax_w(t);
        l += p;

        // weighted accumulate (row still in registers)
        acc[0].x = fmaf(p, v0.x, acc[0].x); acc[0].y = fmaf(p, v0.y, acc[0].y);
        acc[0].z = fmaf(p, v0.z, acc[0].z); acc[0].w = fmaf(p, v0.w, acc[0].w);
        acc[1].x = fmaf(p, v1.x, acc[1].x); acc[1].y = fmaf(p, v1.y, acc[1].y);
        acc[1].z = fmaf(p, v1.z, acc[1].z); acc[1].w = fmaf(p, v1.w, acc[1].w);
        acc[2].x = fmaf(p, v2.x, acc[2].x); acc[2].y = fmaf(p, v2.y, acc[2].y);
        acc[2].z = fmaf(p, v2.z, acc[2].z); acc[2].w = fmaf(p, v2.w, acc[2].w);
        acc[3].x = fmaf(p, v3.x, acc[3].x); acc[3].y = fmaf(p, v3.y, acc[3].y);
        acc[3].z = fmaf(p, v3.z, acc[3].z); acc[3].w = fmaf(p, v3.w, acc[3].w);
    }

    // Block-level reduce across the 4 waves; reuse first 16 KB of the ring.
    __syncthreads();                       // all DMAs drained (vmcnt(0) at r=31)
    float* lds_c = smem;
#pragma unroll
    for (int k = 0; k < 4; ++k)
        *(float4*)(lds_c + wave * HH + k * 256 + lane * 4) = acc[k];
    if (lane == 0) lds_l[wave] = l;        // l is lane-replicated in a wave
    __syncthreads();

    float4 c = *(const float4*)(lds_c + tid * 4);
#pragma unroll
    for (int wv2 = 1; wv2 < WAVES; ++wv2) {
        float4 o = *(const float4*)(lds_c + wv2 * HH + tid * 4);
        c.x += o.x; c.y += o.y; c.z += o.z; c.w += o.w;
    }
    *(float4*)(pc + (long long)blk * HH + tid * 4) = c;
    if (tid == 0)
        pl[blk] = lds_l[0] + lds_l[1] + lds_l[2] + lds_l[3];
}

// Pass 2: combine CHUNKS partials per batch, normalize.
__global__ __launch_bounds__(256) void attn_pass2(
    const float* __restrict__ pc, const float* __restrict__ pl,
    float* __restrict__ out)
{
    const int b = blockIdx.x;
    const int t = threadIdx.x;
    float l = 0.f;
    float4 c = make_float4(0.f, 0.f, 0.f, 0.f);
#pragma unroll
    for (int i = 0; i < CHUNKS; ++i) {
        const int blk = b * CHUNKS + i;
        l += pl[blk];
        float4 o = *(const float4*)(pc + (long long)blk * HH + t * 4);
        c.x += o.x; c.y += o.y; c.z += o.z; c.w += o.w;
    }
    const float inv = 1.f / l;
    float4 r = make_float4(c.x * inv, c.y * inv, c.z * inv, c.w * inv);
    *(float4*)(out + (long long)b * HH + t * 4) = r;
}

extern "C" void kernel_launch(void* const* d_in, const int* in_sizes, int n_in,
                              void* d_out, int out_size, void* d_ws, size_t ws_size,
                              hipStream_t stream) {
    const float* x = (const float*)d_in[0];   // [B,S,H] fp32
    const float* w = (const float*)d_in[1];   // [H] fp32
    float* out = (float*)d_out;               // [B,H] fp32

    float* pc = (float*)d_ws;                           // [B*CHUNKS, H]
    float* pl = pc + (size_t)BB * CHUNKS * HH;          // [B*CHUNKS]

    attn_pass1<<<BB * CHUNKS, 256, 0, stream>>>(x, w, pc, pl);
    attn_pass2<<<BB, 256, 0, stream>>>(pc, pl, out);
}